// Round 11
// baseline (45.111 us; speedup 1.0000x reference)
//
#include <hip/hip_runtime.h>

// Problem constants (match reference)
#define NB 4
#define LL 2048
#define NH 12
#define DD 64
#define CB 128                 // chunk size (== reference chunk; math identical)
#define NG (LL/CB)             // 16 chunks
#define NBH (NB*NH)            // 48
#define ST_BYTES (DD*DD*2)     // 8 KB: per-chunk state bf16 [m][d]

// ws layout:
//   [0, ST2_OFF)            raw chunk states, linear [m][d] bf16   (K1 w, scan r)
//   [ST2_OFF, KS_OFF)       scanned states, SWZ8 byte image        (scan w, K3 r)
//   [KS_OFF, KPRE_OFF)      ksum f32, raw -> exclusive in place    (K1 w, scan rw, K3 r)
//   [KPRE_OFF, VTPRE_OFF)   phi(k) bf16 row-major SWZ8 image, 16KB/chunk (K1 w, K3 r)
//   [VTPRE_OFF, ...)        VT bf16 [m][r] SWZ16 image, 16KB/chunk       (K1 w, K3 r)
#define ST2_OFF   ((size_t)NBH*NG*ST_BYTES)
#define KS_OFF    (ST2_OFF + (size_t)NBH*NG*ST_BYTES)
#define KPRE_OFF  (KS_OFF + (size_t)NBH*NG*DD*4)
#define PRE_BYTES ((size_t)16384)
#define VTPRE_OFF (KPRE_OFF + (size_t)NBH*NG*PRE_BYTES)

typedef short bf16x8 __attribute__((ext_vector_type(8)));
typedef float f32x4  __attribute__((ext_vector_type(4)));

#define SWZ8(row, x)  ((x) ^ (((row) & 7) << 4))    // swizzle within 128B rows
#define SWZ16(row, x) ((x) ^ (((row) & 15) << 4))   // swizzle within 256B rows

__device__ __forceinline__ float phi(float x) {
    return x > 0.0f ? x + 1.0f : __expf(x);          // elu(x)+1
}
__device__ __forceinline__ unsigned f2bf1(float x) { // f32 -> bf16 bits (RNE)
    union { float f; unsigned u; } v; v.f = x;
    return (v.u + 0x7FFFu + ((v.u >> 16) & 1u)) >> 16;
}
__device__ __forceinline__ unsigned packbf(float a, float b) {
    return f2bf1(a) | (f2bf1(b) << 16);
}
__device__ __forceinline__ float bf2f(unsigned short u) {
    union { unsigned u; float f; } v; v.u = ((unsigned)u) << 16; return v.f;
}
__device__ __forceinline__ void addbf8(float* run, uint4 a) {
    const unsigned u[4] = {a.x, a.y, a.z, a.w};
    #pragma unroll
    for (int i = 0; i < 4; ++i) {
        run[2*i+0] += bf2f((unsigned short)(u[i] & 0xffffu));
        run[2*i+1] += bf2f((unsigned short)(u[i] >> 16));
    }
}
__device__ __forceinline__ uint4 pack8(const float* run) {
    uint4 s;
    s.x = packbf(run[0], run[1]); s.y = packbf(run[2], run[3]);
    s.z = packbf(run[4], run[5]); s.w = packbf(run[6], run[7]);
    return s;
}

// ---------------- Kernel 1: per-chunk state + ksum; ALSO exports the bf16 byte
// images K3 needs (K row-major SWZ8, VT SWZ16) so K3's staging is a pure memcpy.
__global__ __launch_bounds__(256) void la_chunk_sums(
    const float* __restrict__ kin, const float* __restrict__ vin,
    char* __restrict__ wsb)
{
    __shared__ __align__(16) char sm[32768];  // KT [d][r] 0..16K | VT [m][r] 16..32K
    const int bid = blockIdx.x;
    const int g = bid & (NG-1);
    const int h = (bid >> 4) % NH;
    const int n = bid / (NG*NH);
    const int t = threadIdx.x;
    const int l0 = g * CB;
    const int w = t >> 6, l = t & 63, gq = l >> 4, c16 = l & 15;

    char* kpre  = wsb + KPRE_OFF  + (size_t)bid * PRE_BYTES;
    char* vtpre = wsb + VTPRE_OFF + (size_t)bid * PRE_BYTES;

    // stage phi(k), v transposed (LDS) + export K row-major bf16 image (global)
    #pragma unroll
    for (int p = 0; p < 8; ++p) {
        const int i = p*256 + t;
        const int r = i >> 4, c4 = i & 15;
        const size_t gidx = ((size_t)((n*LL + l0 + r)*NH + h))*DD + c4*4;
        float4 kk = *(const float4*)(kin + gidx);
        float4 vl = *(const float4*)(vin + gidx);
        const float kf[4] = {phi(kk.x), phi(kk.y), phi(kk.z), phi(kk.w)};
        const float vf[4] = {vl.x, vl.y, vl.z, vl.w};
        uint2 kp; kp.x = packbf(kf[0], kf[1]); kp.y = packbf(kf[2], kf[3]);
        *(uint2*)(kpre + r*128 + SWZ8(r, c4*8)) = kp;   // coalesces per 128B row
        #pragma unroll
        for (int j = 0; j < 4; ++j) {
            const int d = c4*4 + j;
            *(unsigned short*)(sm +         d*256 + SWZ16(d, 2*r)) = (unsigned short)f2bf1(kf[j]);
            *(unsigned short*)(sm + 16384 + d*256 + SWZ16(d, 2*r)) = (unsigned short)f2bf1(vf[j]);
        }
    }
    __syncthreads();

    const int m = 16*w + c16;
    bf16x8 va[4];
    #pragma unroll
    for (int ks = 0; ks < 4; ++ks)
        va[ks] = *(const bf16x8*)(sm + 16384 + m*256 + SWZ16(m, 64*ks + 16*gq));
    const short one = (short)0x3F80;
    const bf16x8 ones = {one, one, one, one, one, one, one, one};

    f32x4 acc[4], ksa[4];
    #pragma unroll
    for (int td = 0; td < 4; ++td) {
        acc[td] = (f32x4){0.f,0.f,0.f,0.f};
        ksa[td] = (f32x4){0.f,0.f,0.f,0.f};
    }
    #pragma unroll
    for (int td = 0; td < 4; ++td) {
        const int d = 16*td + c16;
        #pragma unroll
        for (int ks = 0; ks < 4; ++ks) {
            const bf16x8 kb = *(const bf16x8*)(sm + d*256 + SWZ16(d, 64*ks + 16*gq));
            acc[td] = __builtin_amdgcn_mfma_f32_16x16x32_bf16(va[ks], kb, acc[td], 0, 0, 0);
            ksa[td] = __builtin_amdgcn_mfma_f32_16x16x32_bf16(ones,  kb, ksa[td], 0, 0, 0);
        }
    }

    // export VT byte image (LDS region is exactly what K3 wants; linear dump)
    #pragma unroll
    for (int p = 0; p < 4; ++p) {
        const int i = p*256 + t;
        *(uint4*)(vtpre + i*16) = *(const uint4*)(sm + 16384 + i*16);
    }

    // direct global stores: raw state bf16 [m][d], linear (L2 merges 32B runs)
    char* stg = wsb + (size_t)bid * ST_BYTES;
    #pragma unroll
    for (int td = 0; td < 4; ++td)
        #pragma unroll
        for (int e = 0; e < 4; ++e) {
            const int mr = 16*w + 4*gq + e;      // C row = m
            const int d  = 16*td + c16;          // C col = d
            *(unsigned short*)(stg + mr*128 + d*2) = (unsigned short)f2bf1(acc[td][e]);
        }
    if (w == 0 && gq == 0) {   // raw ksum f32 (all C-rows equal; take e=0)
        float* ksw = (float*)(wsb + KS_OFF) + (size_t)bid * DD;
        #pragma unroll
        for (int td = 0; td < 4; ++td)
            ksw[16*td + c16] = ksa[td][0];
    }
}

// ---------------- Kernel 2: exclusive prefix scan over chunks (per n,h).
// State: reads raw linear, writes scanned at SWZ8 image into ST2 (separate
// region -> no in-place race from the address permutation). ksum: in place.
__global__ __launch_bounds__(256) void la_scan(char* __restrict__ wsb)
{
    const int nh = blockIdx.x / 3;
    const int sl = blockIdx.x % 3;
    const int t  = threadIdx.x;
    if (sl < 2) {
        const int t4 = sl*256 + t;                 // uint4 slot 0..511 of 8KB chunk
        const int mr = t4 >> 3, cc = t4 & 7;
        const char* rbase = wsb + (size_t)nh * NG * ST_BYTES + (size_t)t4 * 16;
        char*       wbase = wsb + ST2_OFF + (size_t)nh * NG * ST_BYTES
                            + mr*128 + SWZ8(mr, cc*16);
        float run[8];
        #pragma unroll
        for (int i = 0; i < 8; ++i) run[i] = 0.f;
        #pragma unroll
        for (int g2 = 0; g2 < NG; g2 += 2) {
            uint4 a0 = *(const uint4*)(rbase + (size_t)(g2+0)*ST_BYTES);
            uint4 a1 = *(const uint4*)(rbase + (size_t)(g2+1)*ST_BYTES);
            *(uint4*)(wbase + (size_t)(g2+0)*ST_BYTES) = pack8(run);
            addbf8(run, a0);
            *(uint4*)(wbase + (size_t)(g2+1)*ST_BYTES) = pack8(run);
            addbf8(run, a1);
        }
    } else if (t < DD) {
        float* base = (float*)(wsb + KS_OFF) + (size_t)nh * NG * DD + t;
        float run = 0.f;
        #pragma unroll
        for (int g4 = 0; g4 < NG; g4 += 4) {
            float a0 = base[(g4+0)*DD], a1 = base[(g4+1)*DD];
            float a2 = base[(g4+2)*DD], a3 = base[(g4+3)*DD];
            base[(g4+0)*DD] = run; run += a0;
            base[(g4+1)*DD] = run; run += a1;
            base[(g4+2)*DD] = run; run += a2;
            base[(g4+3)*DD] = run; run += a3;
        }
    }
}

// ---------------- Kernel 3: per-chunk output via MFMA, 512 threads (8 waves).
// Staging is now: phi(q) pack (1/3 of old VALU) + pure linear memcpys for
// K / VT / STX (pre-swizzled byte images from K1 / scan).
#define SM_Q   0
#define SM_K   16384
#define SM_S   0
#define SM_VT  32768
#define SM_STX 49152
#define SM_KSX 57344
#define SM_ZL  57600
#define SM_BYTES 58112

__global__ __launch_bounds__(512) void la_output(
    const float* __restrict__ qin, const char* __restrict__ wsb,
    float* __restrict__ out)
{
    __shared__ __align__(16) char sm[SM_BYTES];
    const int bid = blockIdx.x;
    const int g = bid & (NG-1);
    const int h = (bid >> 4) % NH;
    const int n = bid / (NG*NH);
    const int t = threadIdx.x;
    const int l0 = g * CB;
    const int w = t >> 6, l = t & 63, gq = l >> 4, c16 = l & 15;
    const int c = 16*w + c16;            // this lane's column (query row) 0..127

    // ---- stage phi(q) (only remaining transform) ----
    #pragma unroll
    for (int p = 0; p < 4; ++p) {
        const int i = p*512 + t;
        const int r = i >> 4, c4 = i & 15;
        const size_t gidx = ((size_t)((n*LL + l0 + r)*NH + h))*DD + c4*4;
        float4 qq = *(const float4*)(qin + gidx);
        uint2 qp; qp.x = packbf(phi(qq.x), phi(qq.y)); qp.y = packbf(phi(qq.z), phi(qq.w));
        *(uint2*)(sm + SM_Q + r*128 + SWZ8(r, c4*8)) = qp;
    }
    // ---- pure memcpy staging: K (16K), VT (16K), STX (8K) ----
    {
        const char* kpre  = wsb + KPRE_OFF  + (size_t)bid * PRE_BYTES;
        const char* vtpre = wsb + VTPRE_OFF + (size_t)bid * PRE_BYTES;
        const char* st2   = wsb + ST2_OFF   + (size_t)bid * ST_BYTES;
        #pragma unroll
        for (int p = 0; p < 2; ++p) {
            const int i = (p*512 + t) * 16;
            *(uint4*)(sm + SM_K  + i) = *(const uint4*)(kpre  + i);
            *(uint4*)(sm + SM_VT + i) = *(const uint4*)(vtpre + i);
        }
        *(uint4*)(sm + SM_STX + t*16) = *(const uint4*)(st2 + t*16);
    }
    if (t < DD)
        ((float*)(sm + SM_KSX))[t] =
            ((const float*)(wsb + KS_OFF))[(size_t)bid * DD + t];
    __syncthreads();

    // ---- q fragments (kept in regs through both phases) ----
    const bf16x8 qf0 = *(const bf16x8*)(sm + SM_Q + c*128 + SWZ8(c, 16*gq));
    const bf16x8 qf1 = *(const bf16x8*)(sm + SM_Q + c*128 + SWZ8(c, 64 + 16*gq));

    // ---- scores: S^T tiles, 8 r-tiles of 16 ----
    f32x4 sreg[8];
    #pragma unroll
    for (int tr = 0; tr < 8; ++tr) {
        const int r = 16*tr + c16;
        const bf16x8 ka0 = *(const bf16x8*)(sm + SM_K + r*128 + SWZ8(r, 16*gq));
        const bf16x8 ka1 = *(const bf16x8*)(sm + SM_K + r*128 + SWZ8(r, 64 + 16*gq));
        f32x4 a; a[0]=0.f; a[1]=0.f; a[2]=0.f; a[3]=0.f;
        a = __builtin_amdgcn_mfma_f32_16x16x32_bf16(ka0, qf0, a, 0, 0, 0);
        a = __builtin_amdgcn_mfma_f32_16x16x32_bf16(ka1, qf1, a, 0, 0, 0);
        sreg[tr] = a;
    }
    // causal mask (keep r <= c) + z intra partial
    float z = 0.f;
    #pragma unroll
    for (int tr = 0; tr < 8; ++tr)
        #pragma unroll
        for (int e = 0; e < 4; ++e) {
            const int rr = 16*tr + 4*gq + e;
            if (rr <= c) z += sreg[tr][e]; else sreg[tr][e] = 0.f;
        }
    // z inter partial from qf regs (lane holds d=8gq+[0,8) and 32+8gq+[0,8))
    {
        const float* ksxf = (const float*)(sm + SM_KSX);
        #pragma unroll
        for (int i = 0; i < 8; ++i) {
            z += bf2f((unsigned short)qf0[i]) * ksxf[8*gq + i];
            z += bf2f((unsigned short)qf1[i]) * ksxf[32 + 8*gq + i];
        }
    }
    z += __shfl_xor(z, 16);
    z += __shfl_xor(z, 32);
    __syncthreads();   // all Q/K LDS reads done before S overlays them

    // ---- write masked S bf16 as S[c][r] (256B rows, SWZ16) ----
    #pragma unroll
    for (int tr = 0; tr < 8; ++tr) {
        uint2 sp; sp.x = packbf(sreg[tr][0], sreg[tr][1]); sp.y = packbf(sreg[tr][2], sreg[tr][3]);
        *(uint2*)(sm + SM_S + c*256 + SWZ16(c, 32*tr + 8*gq)) = sp;
    }
    if (gq == 0) ((float*)(sm + SM_ZL))[c] = z;
    __syncthreads();

    // ---- PV intra (k=r, 4 steps) + inter (k=d, 2 steps) ----
    bf16x8 sf[4];
    #pragma unroll
    for (int ks = 0; ks < 4; ++ks)
        sf[ks] = *(const bf16x8*)(sm + SM_S + c*256 + SWZ16(c, 64*ks + 16*gq));
    f32x4 acc[4];
    #pragma unroll
    for (int tm = 0; tm < 4; ++tm) { acc[tm][0]=0.f; acc[tm][1]=0.f; acc[tm][2]=0.f; acc[tm][3]=0.f; }
    #pragma unroll
    for (int tm = 0; tm < 4; ++tm) {
        const int m = 16*tm + c16;
        #pragma unroll
        for (int ks = 0; ks < 4; ++ks) {
            const bf16x8 vf = *(const bf16x8*)(sm + SM_VT + m*256 + SWZ16(m, 64*ks + 16*gq));
            acc[tm] = __builtin_amdgcn_mfma_f32_16x16x32_bf16(sf[ks], vf, acc[tm], 0, 0, 0);
        }
        const bf16x8 st0 = *(const bf16x8*)(sm + SM_STX + m*128 + SWZ8(m, 16*gq));
        const bf16x8 st1 = *(const bf16x8*)(sm + SM_STX + m*128 + SWZ8(m, 64 + 16*gq));
        acc[tm] = __builtin_amdgcn_mfma_f32_16x16x32_bf16(qf0, st0, acc[tm], 0, 0, 0);
        acc[tm] = __builtin_amdgcn_mfma_f32_16x16x32_bf16(qf1, st1, acc[tm], 0, 0, 0);
    }

    // ---- epilogue ----
    float zinv[4];
    #pragma unroll
    for (int e = 0; e < 4; ++e) {
        const float zr = ((const float*)(sm + SM_ZL))[16*w + 4*gq + e];
        zinv[e] = 1.0f / (zr + 1e-6f);
    }
    #pragma unroll
    for (int tm = 0; tm < 4; ++tm)
        #pragma unroll
        for (int e = 0; e < 4; ++e) {
            const int cr = 16*w + 4*gq + e;
            const int m  = 16*tm + c16;
            out[((size_t)((n*LL + l0 + cr)*NH + h))*DD + m] = acc[tm][e] * zinv[e];
        }
}

extern "C" void kernel_launch(void* const* d_in, const int* in_sizes, int n_in,
                              void* d_out, int out_size, void* d_ws, size_t ws_size,
                              hipStream_t stream) {
    const float* q = (const float*)d_in[0];
    const float* k = (const float*)d_in[1];
    const float* v = (const float*)d_in[2];
    float* out = (float*)d_out;
    char* wsb  = (char*)d_ws;   // ~38 MB used: states raw+scanned, ksum, K/VT bf16 images

    const int nblk = NB * NH * NG;   // 768
    la_chunk_sums<<<nblk, 256, 0, stream>>>(k, v, wsb);
    la_scan<<<NBH*3, 256, 0, stream>>>(wsb);
    la_output<<<nblk, 512, 0, stream>>>(q, wsb, out);
}